// Round 7
// baseline (79.519 us; speedup 1.0000x reference)
//
#include <hip/hip_runtime.h>
#include <hip/hip_bf16.h>
#include <stdint.h>

typedef short bf16x8 __attribute__((ext_vector_type(8)));
typedef float f32x4 __attribute__((ext_vector_type(4)));

#define D  512
#define NB 4096
#define NT 8192

__device__ __forceinline__ unsigned short f2bf(float f) {
    __hip_bfloat16 h = __float2bfloat16(f);
    return *reinterpret_cast<unsigned short*>(&h);
}

// Fused fp32->bf16 convert + row squared-norm for BOTH inputs; x rows also
// write the fp32 passthrough (output 0). One wave per row. HBM-floor bound.
__global__ __launch_bounds__(256) void prep_kernel(
    const float* __restrict__ x, const float* __restrict__ y,
    unsigned short* __restrict__ xb, unsigned short* __restrict__ yb,
    float* __restrict__ x2, float* __restrict__ y2, float* __restrict__ copy)
{
    const int grow = blockIdx.x * 4 + (threadIdx.x >> 6);
    const int lane = threadIdx.x & 63;
    const bool isX = grow < NB;
    const int row  = isX ? grow : grow - NB;
    const float* src = isX ? x : y;
    unsigned short* dst = isX ? xb : yb;
    float* norms = isX ? x2 : y2;

    const float4* rp = reinterpret_cast<const float4*>(src + (size_t)row * D);
    float4 v0 = rp[lane * 2];
    float4 v1 = rp[lane * 2 + 1];
    if (isX) {
        f32x4* cp = reinterpret_cast<f32x4*>(copy + (size_t)row * D);
        __builtin_nontemporal_store((f32x4){v0.x, v0.y, v0.z, v0.w}, cp + lane * 2);
        __builtin_nontemporal_store((f32x4){v1.x, v1.y, v1.z, v1.w}, cp + lane * 2 + 1);
    }
    float s = v0.x*v0.x + v0.y*v0.y + v0.z*v0.z + v0.w*v0.w
            + v1.x*v1.x + v1.y*v1.y + v1.z*v1.z + v1.w*v1.w;
    union { unsigned short h[8]; int4 v; } u;
    u.h[0] = f2bf(v0.x); u.h[1] = f2bf(v0.y); u.h[2] = f2bf(v0.z); u.h[3] = f2bf(v0.w);
    u.h[4] = f2bf(v1.x); u.h[5] = f2bf(v1.y); u.h[6] = f2bf(v1.z); u.h[7] = f2bf(v1.w);
    reinterpret_cast<int4*>(dst + (size_t)row * D)[lane] = u.v;
    #pragma unroll
    for (int off = 32; off > 0; off >>= 1) s += __shfl_xor(s, off);
    if (lane == 0) norms[row] = s;
}

// 128x256 tile, BK=32, 4 waves (1Mx4N, wave-tile 128x64), 3 rotating LDS
// buffers, SINGLE barrier per phase (2/KT): all ds_reads retire via
// lgkmcnt(0) BEFORE the barrier and the per-KT vmcnt checkpoint is also
// pre-barrier, so the barrier simultaneously (a) protects write-after-read
// (stage target = buffer read one phase ago, reads retired pre-barrier) and
// (b) publishes stage landings (each wave's vmcnt wait + barrier). Sim
// output uses non-temporal stores so the 134 MB stream doesn't evict the
// A/B panels from per-XCD L2. 72 KiB LDS -> 2 blocks/CU.
// LDS (ushort): buf b at b*12288: A 128x32 @+0 (8 KB), B 256x32 @+4096 (16 KB).
__global__ __launch_bounds__(256, 2) void gemm_sim_kernel(
    const unsigned short* __restrict__ X, const unsigned short* __restrict__ Y,
    const float* __restrict__ x2, const float* __restrict__ y2,
    float* __restrict__ out)
{
    __shared__ alignas(16) unsigned short lds[36864];   // 72 KiB

    const int t    = threadIdx.x;
    const int lane = t & 63;
    const int w    = t >> 6;          // 0..3, wave col (64 cols each)

    // XCD swizzle, L2-fit: each XCD covers 16 rowTiles x 8 colTiles
    // (A 2 MB + B 2 MB = 4 MB = per-XCD L2; stores bypass via nt).
    const int bid = blockIdx.x;
    const int xcd = bid & 7;
    const int idx = bid >> 3;                          // 0..127
    const int rowBase = ((xcd >> 2) * 16 + (idx & 15)) * 128;
    const int colBase = ((xcd & 3) * 8 + (idx >> 4)) * 256;

    // Staging: thread t writes 16 B chunks at LDS ushort off t*8 (+L*2048).
    // Chunk-XOR swizzle (rule #21): stored chunk c' holds global chunk
    // c' ^ ((row>>1)&3); folds to t-only constants for all L.
    const int swz = ((t & 3) ^ ((t >> 3) & 3)) * 8;
    const unsigned short* gA = X + (size_t)(rowBase + (t >> 2)) * D + swz;
    const unsigned short* gB = Y + (size_t)(colBase + (t >> 2)) * D + swz;

    // Read side: swizzle folds to a per-lane constant.
    const int cread = ((lane >> 4) ^ ((lane >> 1) & 3)) * 8;
    const int aoff = (lane & 15) * 32 + cread;                    // + buf + mh*2048 + m*512
    const int boff = 4096 + (w * 64 + (lane & 15)) * 32 + cread;  // + buf + n*512

    f32x4 acc[8][4] = {};
    bf16x8 bfr[4];

#define STAGE_A(BUF, KT) do { \
    _Pragma("unroll") \
    for (int L = 0; L < 2; ++L) \
        __builtin_amdgcn_global_load_lds( \
            (const __attribute__((address_space(1))) void*)(gA + (size_t)L * 64 * D + (KT) * 32), \
            (__attribute__((address_space(3))) void*)(lds + (BUF) * 12288 + t * 8 + L * 2048), 16, 0, 0); \
} while (0)

#define STAGE_B(BUF, KT) do { \
    _Pragma("unroll") \
    for (int L = 0; L < 4; ++L) \
        __builtin_amdgcn_global_load_lds( \
            (const __attribute__((address_space(1))) void*)(gB + (size_t)L * 64 * D + (KT) * 32), \
            (__attribute__((address_space(3))) void*)(lds + (BUF) * 12288 + 4096 + t * 8 + L * 2048), 16, 0, 0); \
} while (0)

// Phase A of a K-tile: B-frags + A-frags(mh0), stage A(kt+2), retire reads,
// barrier, 16 MFMA. Phase B: A-frags(mh1), stage B(kt+2), per-KT checkpoint
// (lgkm + counted vmcnt) pre-barrier, barrier, 16 MFMA.
#define PHASE(BUF, MH, STG, WAITS) do { \
    bf16x8 _a[4]; \
    if ((MH) == 0) { \
        _Pragma("unroll") \
        for (int n = 0; n < 4; ++n) \
            bfr[n] = *(const bf16x8*)(lds + (BUF) * 12288 + boff + n * 512); \
    } \
    _Pragma("unroll") \
    for (int m = 0; m < 4; ++m) \
        _a[m] = *(const bf16x8*)(lds + (BUF) * 12288 + aoff + (MH) * 2048 + m * 512); \
    STG; \
    WAITS; \
    __builtin_amdgcn_s_barrier(); \
    __builtin_amdgcn_s_setprio(1); \
    _Pragma("unroll") \
    for (int m = 0; m < 4; ++m) { \
        _Pragma("unroll") \
        for (int n = 0; n < 4; ++n) \
            acc[(MH) * 4 + m][n] = __builtin_amdgcn_mfma_f32_16x16x32_bf16(_a[m], bfr[n], acc[(MH) * 4 + m][n], 0, 0, 0); \
    } \
    __builtin_amdgcn_s_setprio(0); \
} while (0)

    // Prologue: kt0 + kt1 staged (12 loads); vmcnt(6) -> kt0 landed.
    STAGE_A(0, 0); STAGE_B(0, 0);
    STAGE_A(1, 1); STAGE_B(1, 1);
    asm volatile("s_waitcnt vmcnt(6)" ::: "memory");
    __builtin_amdgcn_s_barrier();

    // 16 K-tiles, buffer = kt%3. Phase A stages A(kt+2); phase B stages
    // B(kt+2) then checkpoints: outstanding = kt+1's 6 + kt+2's 6 -> vmcnt(6)
    // retires kt+1 (read next KT). kt=14 drains all (kt15 staged), kt=15 none.
#pragma unroll
    for (int kt = 0; kt < 16; ++kt) {
        PHASE((kt % 3), 0,
              if (kt + 2 < 16) STAGE_A(((kt + 2) % 3), kt + 2),
              asm volatile("s_waitcnt lgkmcnt(0)" ::: "memory"));
        PHASE((kt % 3), 1,
              if (kt + 2 < 16) STAGE_B(((kt + 2) % 3), kt + 2),
              if (kt < 14)      { asm volatile("s_waitcnt lgkmcnt(0) vmcnt(6)" ::: "memory"); }
              else if (kt == 14){ asm volatile("s_waitcnt lgkmcnt(0) vmcnt(0)" ::: "memory"); }
              else              { asm volatile("s_waitcnt lgkmcnt(0)" ::: "memory"); });
    }
#undef PHASE
#undef STAGE_A
#undef STAGE_B

    // Epilogue: C/D layout col = lane&15, row = (lane>>4)*4 + reg.
    // Non-temporal stores: output is write-once, never re-read -> keep L2
    // clean for the co-resident block's A/B panels.
    const int col0 = colBase + w * 64 + (lane & 15);
    const int row0 = rowBase + ((lane >> 4) << 2);
    #pragma unroll
    for (int mi = 0; mi < 8; ++mi) {
        const int rbase = row0 + (mi >> 2) * 64 + (mi & 3) * 16;
        #pragma unroll
        for (int q = 0; q < 4; ++q) {
            const int grow = rbase + q;
            const float xn = x2[grow];
            float* orow = out + (size_t)grow * NT;
            #pragma unroll
            for (int n = 0; n < 4; ++n) {
                const int gcol = col0 + n * 16;
                float sq = fmaxf(xn + y2[gcol] - 2.0f * acc[mi][n][q], 0.0f);
                __builtin_nontemporal_store(fminf(rsqrtf(sq), 1.0e6f), orow + gcol);
            }
        }
    }
}

extern "C" void kernel_launch(void* const* d_in, const int* in_sizes, int n_in,
                              void* d_out, int out_size, void* d_ws, size_t ws_size,
                              hipStream_t stream)
{
    const float* x = (const float*)d_in[0];
    const float* y = (const float*)d_in[1];
    float* out = (float*)d_out;
    char* ws = (char*)d_ws;

    unsigned short* xb = (unsigned short*)ws;                 // 4 MB
    unsigned short* yb = (unsigned short*)(ws + (4u << 20));  // 8 MB
    float* x2 = (float*)(ws + (12u << 20));                   // 16 KB
    float* y2 = (float*)(ws + (12u << 20) + 4 * NB);          // 32 KB

    prep_kernel<<<(NB + NT) / 4, 256, 0, stream>>>(x, y, xb, yb, x2, y2, out);
    gemm_sim_kernel<<<1024, 256, 0, stream>>>(xb, yb, x2, y2, out + (size_t)NB * D);
}

// Round 8
// 64.959 us; speedup vs baseline: 1.2241x; 1.2241x over previous
//
#include <hip/hip_runtime.h>
#include <hip/hip_bf16.h>
#include <stdint.h>

typedef short bf16x8 __attribute__((ext_vector_type(8)));
typedef float f32x4 __attribute__((ext_vector_type(4)));

#define D  512
#define NB 4096
#define NT 8192

__device__ __forceinline__ unsigned short f2bf(float f) {
    __hip_bfloat16 h = __float2bfloat16(f);
    return *reinterpret_cast<unsigned short*>(&h);
}

// Fused fp32->bf16 convert + row squared-norm for BOTH inputs; x rows also
// write the fp32 passthrough (output 0). One wave per row. HBM-floor bound.
__global__ __launch_bounds__(256) void prep_kernel(
    const float* __restrict__ x, const float* __restrict__ y,
    unsigned short* __restrict__ xb, unsigned short* __restrict__ yb,
    float* __restrict__ x2, float* __restrict__ y2, float* __restrict__ copy)
{
    const int grow = blockIdx.x * 4 + (threadIdx.x >> 6);
    const int lane = threadIdx.x & 63;
    const bool isX = grow < NB;
    const int row  = isX ? grow : grow - NB;
    const float* src = isX ? x : y;
    unsigned short* dst = isX ? xb : yb;
    float* norms = isX ? x2 : y2;

    const float4* rp = reinterpret_cast<const float4*>(src + (size_t)row * D);
    float4 v0 = rp[lane * 2];
    float4 v1 = rp[lane * 2 + 1];
    if (isX) {
        float4* cp = reinterpret_cast<float4*>(copy + (size_t)row * D);
        cp[lane * 2]     = v0;
        cp[lane * 2 + 1] = v1;
    }
    float s = v0.x*v0.x + v0.y*v0.y + v0.z*v0.z + v0.w*v0.w
            + v1.x*v1.x + v1.y*v1.y + v1.z*v1.z + v1.w*v1.w;
    union { unsigned short h[8]; int4 v; } u;
    u.h[0] = f2bf(v0.x); u.h[1] = f2bf(v0.y); u.h[2] = f2bf(v0.z); u.h[3] = f2bf(v0.w);
    u.h[4] = f2bf(v1.x); u.h[5] = f2bf(v1.y); u.h[6] = f2bf(v1.z); u.h[7] = f2bf(v1.w);
    reinterpret_cast<int4*>(dst + (size_t)row * D)[lane] = u.v;
    #pragma unroll
    for (int off = 32; off > 0; off >>= 1) s += __shfl_xor(s, off);
    if (lane == 0) norms[row] = s;
}

// 128x256 tile, BK=32, 4 waves (1Mx4N, wave-tile 128x64), counted-vmcnt
// engine, THREE rotating LDS buffers (exact round-5 schedule, 60.6 µs).
// NEW: co-resident-block STAGGER — half the blocks (XOR of blockIdx bits 0
// and 8, separating CU-mates under either dispatch mapping) issue their
// prologue DMA then s_sleep ~6.8 µs before the main loop. This desyncs the
// lockstep twins so one block's epilogue store burst overlaps the other's
// MFMA main loop (in-pipeline overlap is impossible: vmcnt counts stores).
// LDS (ushort): buf b at b*12288: A 128x32 @+0 (8 KB), B 256x32 @+4096 (16 KB).
__global__ __launch_bounds__(256, 2) void gemm_sim_kernel(
    const unsigned short* __restrict__ X, const unsigned short* __restrict__ Y,
    const float* __restrict__ x2, const float* __restrict__ y2,
    float* __restrict__ out)
{
    __shared__ alignas(16) unsigned short lds[36864];   // 72 KiB

    const int t    = threadIdx.x;
    const int lane = t & 63;
    const int w    = t >> 6;          // 0..3, wave col (64 cols each)

    // XCD swizzle, L2-fit: each XCD covers 16 rowTiles x 8 colTiles
    // (A 2 MB + B 2 MB = 4 MB = per-XCD L2).
    const int bid = blockIdx.x;
    const int xcd = bid & 7;
    const int idx = bid >> 3;                          // 0..127
    const int rowBase = ((xcd >> 2) * 16 + (idx & 15)) * 128;
    const int colBase = ((xcd & 3) * 8 + (idx >> 4)) * 256;

    // Staging: thread t writes 16 B chunks at LDS ushort off t*8 (+L*2048).
    // Chunk-XOR swizzle (rule #21): stored chunk c' holds global chunk
    // c' ^ ((row>>1)&3); folds to t-only constants for all L.
    const int swz = ((t & 3) ^ ((t >> 3) & 3)) * 8;
    const unsigned short* gA = X + (size_t)(rowBase + (t >> 2)) * D + swz;
    const unsigned short* gB = Y + (size_t)(colBase + (t >> 2)) * D + swz;

    // Read side: swizzle folds to a per-lane constant.
    const int cread = ((lane >> 4) ^ ((lane >> 1) & 3)) * 8;
    const int aoff = (lane & 15) * 32 + cread;                    // + buf + mh*2048 + m*512
    const int boff = 4096 + (w * 64 + (lane & 15)) * 32 + cread;  // + buf + n*512

    f32x4 acc[8][4] = {};
    bf16x8 bfr[4];

#define STAGE_A(BUF, KT) do { \
    _Pragma("unroll") \
    for (int L = 0; L < 2; ++L) \
        __builtin_amdgcn_global_load_lds( \
            (const __attribute__((address_space(1))) void*)(gA + (size_t)L * 64 * D + (KT) * 32), \
            (__attribute__((address_space(3))) void*)(lds + (BUF) * 12288 + t * 8 + L * 2048), 16, 0, 0); \
} while (0)

#define STAGE_B(BUF, KT) do { \
    _Pragma("unroll") \
    for (int L = 0; L < 4; ++L) \
        __builtin_amdgcn_global_load_lds( \
            (const __attribute__((address_space(1))) void*)(gB + (size_t)L * 64 * D + (KT) * 32), \
            (__attribute__((address_space(3))) void*)(lds + (BUF) * 12288 + 4096 + t * 8 + L * 2048), 16, 0, 0); \
} while (0)

#define PHASE(BUF, MH, STG, CKPT) do { \
    bf16x8 _a[4]; \
    if ((MH) == 0) { \
        _Pragma("unroll") \
        for (int n = 0; n < 4; ++n) \
            bfr[n] = *(const bf16x8*)(lds + (BUF) * 12288 + boff + n * 512); \
    } \
    _Pragma("unroll") \
    for (int m = 0; m < 4; ++m) \
        _a[m] = *(const bf16x8*)(lds + (BUF) * 12288 + aoff + (MH) * 2048 + m * 512); \
    STG; \
    __builtin_amdgcn_s_barrier(); \
    asm volatile("s_waitcnt lgkmcnt(0)" ::: "memory"); \
    __builtin_amdgcn_s_setprio(1); \
    _Pragma("unroll") \
    for (int m = 0; m < 4; ++m) { \
        _Pragma("unroll") \
        for (int n = 0; n < 4; ++n) \
            acc[(MH) * 4 + m][n] = __builtin_amdgcn_mfma_f32_16x16x32_bf16(_a[m], bfr[n], acc[(MH) * 4 + m][n], 0, 0, 0); \
    } \
    __builtin_amdgcn_s_setprio(0); \
    CKPT; \
    __builtin_amdgcn_s_barrier(); \
} while (0)

    // Prologue: kt0 + kt1 staged (12 loads). Stagger half the blocks AFTER
    // issuing the DMA (loads land during the sleep), BEFORE the wait.
    STAGE_A(0, 0); STAGE_B(0, 0);
    STAGE_A(1, 1); STAGE_B(1, 1);
    if (((bid >> 8) ^ bid) & 1) {
        __builtin_amdgcn_s_sleep(127);   // ~8128 cyc
        __builtin_amdgcn_s_sleep(127);   // total ~6.8 µs @2.4 GHz
    }
    asm volatile("s_waitcnt vmcnt(6)" ::: "memory");
    __builtin_amdgcn_s_barrier();

    // 16 K-tiles, buffer = kt%3. Per kt: mh0 phase stages A(kt+2), mh1 phase
    // stages B(kt+2) then checkpoints vmcnt(6) (retires kt+1's 6 loads,
    // leaves kt+2's 6 in flight). Write-after-read: buf[(kt+2)%3] was last
    // read at kt-1, separated by two barriers. Tail: kt=14 drains vmcnt(0).
#pragma unroll
    for (int kt = 0; kt < 16; ++kt) {
        PHASE((kt % 3), 0,
              if (kt + 2 < 16) STAGE_A(((kt + 2) % 3), kt + 2),
              ((void)0));
        PHASE((kt % 3), 1,
              if (kt + 2 < 16) STAGE_B(((kt + 2) % 3), kt + 2),
              if (kt < 14)      { asm volatile("s_waitcnt vmcnt(6)" ::: "memory"); }
              else if (kt == 14){ asm volatile("s_waitcnt vmcnt(0)" ::: "memory"); });
    }
#undef PHASE
#undef STAGE_A
#undef STAGE_B

    // Epilogue: C/D layout col = lane&15, row = (lane>>4)*4 + reg.
    const int col0 = colBase + w * 64 + (lane & 15);
    const int row0 = rowBase + ((lane >> 4) << 2);
    #pragma unroll
    for (int mi = 0; mi < 8; ++mi) {
        const int rbase = row0 + (mi >> 2) * 64 + (mi & 3) * 16;
        #pragma unroll
        for (int q = 0; q < 4; ++q) {
            const int grow = rbase + q;
            const float xn = x2[grow];
            float* orow = out + (size_t)grow * NT;
            #pragma unroll
            for (int n = 0; n < 4; ++n) {
                const int gcol = col0 + n * 16;
                float sq = fmaxf(xn + y2[gcol] - 2.0f * acc[mi][n][q], 0.0f);
                orow[gcol] = fminf(rsqrtf(sq), 1.0e6f);  // rsqrt(0)=inf -> clipped
            }
        }
    }
}

extern "C" void kernel_launch(void* const* d_in, const int* in_sizes, int n_in,
                              void* d_out, int out_size, void* d_ws, size_t ws_size,
                              hipStream_t stream)
{
    const float* x = (const float*)d_in[0];
    const float* y = (const float*)d_in[1];
    float* out = (float*)d_out;
    char* ws = (char*)d_ws;

    unsigned short* xb = (unsigned short*)ws;                 // 4 MB
    unsigned short* yb = (unsigned short*)(ws + (4u << 20));  // 8 MB
    float* x2 = (float*)(ws + (12u << 20));                   // 16 KB
    float* y2 = (float*)(ws + (12u << 20) + 4 * NB);          // 32 KB

    prep_kernel<<<(NB + NT) / 4, 256, 0, stream>>>(x, y, xb, yb, x2, y2, out);
    gemm_sim_kernel<<<1024, 256, 0, stream>>>(xb, yb, x2, y2, out + (size_t)NB * D);
}